// Round 1
// baseline (966.908 us; speedup 1.0000x reference)
//
#include <hip/hip_runtime.h>
#include <hip/hip_bf16.h>

#define NV 40000
#define FD 256
#define HD 128
#define ED 640000
#define NG 3
#define NH (NV*HD)

typedef unsigned short u16;
typedef unsigned int   u32;
typedef __attribute__((ext_vector_type(8))) u16    u16x8;
typedef __attribute__((ext_vector_type(8))) __bf16 bf16x8;
typedef __attribute__((ext_vector_type(4))) float  f32x4;

__device__ inline u16 f2b(float f){ __bf16 h = (__bf16)f; return __builtin_bit_cast(u16, h); }
__device__ inline float b2f(u16 u){ u32 x = ((u32)u)<<16; return __builtin_bit_cast(float, x); }

// ---------------- CSR build ----------------
__global__ void zero_u32(u32* __restrict__ p, long n){
  long i = (long)blockIdx.x*256 + threadIdx.x;
  if (i < n) p[i] = 0u;
}

__global__ void count_k(const int* __restrict__ ei, int* __restrict__ cnt){
  long idx = (long)blockIdx.x*256 + threadIdx.x;
  if (idx >= (long)NG*ED) return;
  int g = (int)(idx / ED);
  int j = (int)(idx - (long)g*ED);
  int c = ei[(long)g*2*ED + ED + j];
  atomicAdd(&cnt[g*NV + c], 1);
}

__global__ void scan_k(const int* __restrict__ cnt, int* __restrict__ cptr,
                       int* __restrict__ cursor, float* __restrict__ dinv){
  int g = blockIdx.x;
  const int* c  = cnt    + (long)g*NV;
  int* pp       = cptr   + (long)g*(NV+1);
  int* cu       = cursor + (long)g*NV;
  float* dv     = dinv   + (long)g*NV;
  __shared__ int wsum[16];
  __shared__ int carrySh;
  int tid = threadIdx.x; int lane = tid & 63; int wv = tid >> 6;
  if (tid == 0) carrySh = 0;
  __syncthreads();
  for (int base = 0; base < NV; base += 1024){
    int i = base + tid;
    int v = (i < NV) ? c[i] : 0;
    int s = v;
    #pragma unroll
    for (int d=1; d<64; d<<=1){ int t2 = __shfl_up(s, d, 64); if (lane >= d) s += t2; }
    if (lane == 63) wsum[wv] = s;
    __syncthreads();
    int carry = carrySh;
    if (wv == 0){
      int t3 = (lane < 16) ? wsum[lane] : 0;
      #pragma unroll
      for (int d=1; d<16; d<<=1){ int u = __shfl_up(t3, d, 64); if (lane >= d) t3 += u; }
      if (lane < 16) wsum[lane] = t3;
    }
    __syncthreads();
    int woff = (wv > 0) ? wsum[wv-1] : 0;
    int incl = s + woff + carry;
    if (i < NV){
      pp[i] = incl - v;
      cu[i] = incl - v;
      dv[i] = rsqrtf((float)(v + 1));
      if (i == NV-1) pp[NV] = incl;
    }
    __syncthreads();
    if (tid == 1023) carrySh = incl;
    __syncthreads();
  }
}

__global__ void fill_k(const int* __restrict__ ei, int* __restrict__ cursor,
                       int* __restrict__ csr){
  long idx = (long)blockIdx.x*256 + threadIdx.x;
  if (idx >= (long)NG*ED) return;
  int g = (int)(idx / ED);
  int j = (int)(idx - (long)g*ED);
  int r = ei[(long)g*2*ED + j];
  int c = ei[(long)g*2*ED + ED + j];
  int pos = atomicAdd(&cursor[g*NV + c], 1);
  csr[(long)g*ED + pos] = r;
}

// --------------- weight transpose: [K][N] f32 -> [N][K] bf16, batched ----------
__global__ void tr_k(const float* __restrict__ src, u16* __restrict__ dst,
                     int K, int NN, long total){
  long idx = (long)blockIdx.x*256 + threadIdx.x;
  if (idx >= total) return;
  long per = (long)K*NN;
  long mat = idx / per; long rem = idx - mat*per;
  int k = (int)(rem / NN), c = (int)(rem - (long)k*NN);
  dst[mat*per + (long)c*K + k] = f2b(src[idx]);
}

// --------------- bf16 MFMA GEMM: C = A @ Bt^T (+bias) -----------------
// A: row-major M x K (f32 if AF32 else bf16). Bt: [N][K] bf16. 128x128 tile, BK=64.
template<int AF32>
__global__ __launch_bounds__(256) void gemm_k(
    const void* __restrict__ A_, long sA,
    const u16* __restrict__ Bt, long sB,
    const float* __restrict__ bias, long sBias,
    float* __restrict__ Cf, long sCf,
    u16* __restrict__ Cb, long sCb,
    int M, int N, int K)
{
  __shared__ __align__(16) u16 lsA[128*64];
  __shared__ __align__(16) u16 lsB[128*64];
  const int gz = blockIdx.z;
  const float* Af = nullptr; const u16* Ab = nullptr;
  if (AF32) Af = (const float*)A_ + (long)gz*sA;
  else      Ab = (const u16*) A_ + (long)gz*sA;
  const u16* Bp = Bt + (long)gz*sB;
  const int t = threadIdx.x;
  const int lane = t & 63, wv = t >> 6, wm = wv >> 1, wn = wv & 1;
  const int lr = lane & 15, lq = lane >> 4;
  const int ar = t >> 1, ah = t & 1;
  const long grow = (long)blockIdx.x*128 + ar;
  const int colB = blockIdx.y*128 + ar;

  f32x4 acc[4][4];
  #pragma unroll
  for (int m=0;m<4;m++)
    #pragma unroll
    for (int n=0;n<4;n++) acc[m][n] = (f32x4)(0.0f);

  for (int k0=0; k0<K; k0+=64){
    if (k0) __syncthreads();
    // ---- stage A (convert to bf16 if f32), rows of the M-tile ----
    u16x8 av[4];
    if (grow < M){
      if (AF32){
        const float4* s = (const float4*)(Af + grow*(long)K + k0 + ah*32);
        #pragma unroll
        for (int i=0;i<4;i++){
          float4 v0 = s[i*2], v1 = s[i*2+1];
          u16x8 w;
          w[0]=f2b(v0.x); w[1]=f2b(v0.y); w[2]=f2b(v0.z); w[3]=f2b(v0.w);
          w[4]=f2b(v1.x); w[5]=f2b(v1.y); w[6]=f2b(v1.z); w[7]=f2b(v1.w);
          av[i] = w;
        }
      } else {
        const u16x8* s = (const u16x8*)(Ab + grow*(long)K + k0 + ah*32);
        #pragma unroll
        for (int i=0;i<4;i++) av[i] = s[i];
      }
    } else {
      #pragma unroll
      for (int i=0;i<4;i++) av[i] = (u16x8)((u16)0);
    }
    #pragma unroll
    for (int i=0;i<4;i++){
      int q = ah*4 + i;
      *(u16x8*)&lsA[ar*64 + ((q ^ (ar&7))<<3)] = av[i];
    }
    // ---- stage B (already bf16 [N][K]) ----
    {
      const u16x8* s = (const u16x8*)(Bp + (long)colB*K + k0 + ah*32);
      #pragma unroll
      for (int i=0;i<4;i++){
        int q = ah*4 + i;
        *(u16x8*)&lsB[ar*64 + ((q ^ (ar&7))<<3)] = s[i];
      }
    }
    __syncthreads();
    // ---- MFMA ----
    #pragma unroll
    for (int kk=0; kk<2; kk++){
      bf16x8 afr[4], bfr[4];
      #pragma unroll
      for (int m=0;m<4;m++){
        int r = wm*64 + m*16 + lr;
        int q = kk*4 + lq;
        afr[m] = __builtin_bit_cast(bf16x8, *(const u16x8*)&lsA[r*64 + ((q ^ (r&7))<<3)]);
      }
      #pragma unroll
      for (int n=0;n<4;n++){
        int r = wn*64 + n*16 + lr;
        int q = kk*4 + lq;
        bfr[n] = __builtin_bit_cast(bf16x8, *(const u16x8*)&lsB[r*64 + ((q ^ (r&7))<<3)]);
      }
      #pragma unroll
      for (int m=0;m<4;m++)
        #pragma unroll
        for (int n=0;n<4;n++)
          acc[m][n] = __builtin_amdgcn_mfma_f32_16x16x32_bf16(afr[m], bfr[n], acc[m][n], 0, 0, 0);
    }
  }
  // ---- epilogue: C/D layout col=lane&15, row=(lane>>4)*4+reg ----
  #pragma unroll
  for (int m=0;m<4;m++){
    long gr0 = (long)blockIdx.x*128 + wm*64 + m*16 + lq*4;
    #pragma unroll
    for (int n=0;n<4;n++){
      int gc = blockIdx.y*128 + wn*64 + n*16 + lr;
      float bb = bias ? bias[gz*sBias + gc] : 0.0f;
      #pragma unroll
      for (int i=0;i<4;i++){
        long gr = gr0 + i;
        if (gr < M){
          float v = acc[m][n][i] + bb;
          if (Cf) Cf[gz*sCf + gr*(long)N + gc] = v;
          if (Cb) Cb[gz*sCb + gr*(long)N + gc] = f2b(v);
        }
      }
    }
  }
}

// --------------- GCN aggregation: one wave per target node ----------------
// out[c] = dinv[c]*( sum_in dinv[r]*xw[r] + dinv[c]*xw[c] ) + bias ; optional relu
__global__ __launch_bounds__(256) void agg_k(
    const u16* __restrict__ xw, long sXW,
    const int* __restrict__ cptr, const int* __restrict__ rows,
    const float* __restrict__ dinv,
    const float* __restrict__ bias, long sBias,
    float* __restrict__ outF, long sOF,
    u16* __restrict__ outB, long sOB,
    int n, int e, int totWaves, int relu)
{
  int wid = (int)((blockIdx.x*256 + threadIdx.x) >> 6);
  if (wid >= totWaves) return;
  int lane = threadIdx.x & 63;
  int g = wid / n;
  int c = wid - g*n;
  const u32* xp = (const u32*)(xw + (long)g*sXW);
  const int* cp = cptr + (long)g*(n+1);
  const int* rw = rows + (long)g*e;
  const float* dv = dinv + (long)g*n;
  float dc = dv[c];
  u32 u = xp[(long)c*64 + lane];
  float sx = dc * b2f((u16)u);
  float sy = dc * b2f((u16)(u>>16));
  int j0 = cp[c], j1 = cp[c+1];
  int j = j0;
  for (; j+4 <= j1; j+=4){
    int r0 = rw[j], r1 = rw[j+1], r2 = rw[j+2], r3 = rw[j+3];
    float w0 = dv[r0], w1 = dv[r1], w2 = dv[r2], w3 = dv[r3];
    u32 v0 = xp[(long)r0*64+lane], v1 = xp[(long)r1*64+lane];
    u32 v2 = xp[(long)r2*64+lane], v3 = xp[(long)r3*64+lane];
    sx += w0*b2f((u16)v0); sy += w0*b2f((u16)(v0>>16));
    sx += w1*b2f((u16)v1); sy += w1*b2f((u16)(v1>>16));
    sx += w2*b2f((u16)v2); sy += w2*b2f((u16)(v2>>16));
    sx += w3*b2f((u16)v3); sy += w3*b2f((u16)(v3>>16));
  }
  for (; j < j1; ++j){
    int r = rw[j]; float w = dv[r];
    u32 v = xp[(long)r*64+lane];
    sx += w*b2f((u16)v); sy += w*b2f((u16)(v>>16));
  }
  float ox = dc*sx + bias[g*sBias + lane*2];
  float oy = dc*sy + bias[g*sBias + lane*2 + 1];
  if (relu){ ox = fmaxf(ox, 0.0f); oy = fmaxf(oy, 0.0f); }
  if (outF) ((float2*)(outF + (long)g*sOF + (long)c*HD))[lane] = make_float2(ox, oy);
  if (outB) ((u32*)(outB + (long)g*sOB))[(long)c*64 + lane] = (u32)f2b(ox) | ((u32)f2b(oy)<<16);
}

// --------------- elementwise ----------------
__global__ void ew_neg2(const float4* __restrict__ a, const float4* __restrict__ b,
                        u16* __restrict__ ob, int n4){
  int i = blockIdx.x*256 + threadIdx.x;
  if (i >= n4) return;
  float4 va = a[i], vb = b[i];
  float x0 = -(va.x+vb.x), x1 = -(va.y+vb.y), x2 = -(va.z+vb.z), x3 = -(va.w+vb.w);
  ((uint2*)ob)[i] = make_uint2((u32)f2b(x0) | ((u32)f2b(x1)<<16),
                               (u32)f2b(x2) | ((u32)f2b(x3)<<16));
}

__global__ void ew_fin(const float4* __restrict__ a, const float4* __restrict__ b,
                       float4* __restrict__ of, u16* __restrict__ ob, int n4){
  int i = blockIdx.x*256 + threadIdx.x;
  if (i >= n4) return;
  float4 va = a[i], vb = b[i];
  float4 v = make_float4(va.x+vb.x, va.y+vb.y, va.z+vb.z, va.w+vb.w);
  of[i] = v;
  ((uint2*)ob)[i] = make_uint2((u32)f2b(v.x) | ((u32)f2b(v.y)<<16),
                               (u32)f2b(v.z) | ((u32)f2b(v.w)<<16));
}

__global__ void softmax_k(float* __restrict__ d, int rows){
  int wid = (blockIdx.x*256 + threadIdx.x) >> 6;
  if (wid >= rows) return;
  int lane = threadIdx.x & 63;
  float4* p = (float4*)(d + (long)wid*FD);
  float4 v = p[lane];
  float m = fmaxf(fmaxf(v.x, v.y), fmaxf(v.z, v.w));
  #pragma unroll
  for (int o=32; o; o>>=1) m = fmaxf(m, __shfl_xor(m, o, 64));
  float e0 = __expf(v.x-m), e1 = __expf(v.y-m), e2 = __expf(v.z-m), e3 = __expf(v.w-m);
  float s = e0+e1+e2+e3;
  #pragma unroll
  for (int o=32; o; o>>=1) s += __shfl_xor(s, o, 64);
  float inv = 1.0f/s;
  p[lane] = make_float4(e0*inv, e1*inv, e2*inv, e3*inv);
}

// ===================== host =====================
extern "C" void kernel_launch(void* const* d_in, const int* in_sizes, int n_in,
                              void* d_out, int out_size, void* d_ws, size_t ws_size,
                              hipStream_t stream)
{
  const float* x    = (const float*)d_in[0];
  const int*   ei   = (const int*)  d_in[1];
  const float* fc1W = (const float*)d_in[2];
  const float* fc1b = (const float*)d_in[3];
  const float* c1W  = (const float*)d_in[4];
  const float* c1b  = (const float*)d_in[5];
  const float* c2W  = (const float*)d_in[6];
  const float* c2b  = (const float*)d_in[7];
  const float* d1W  = (const float*)d_in[8];
  const float* d1b  = (const float*)d_in[9];
  const float* d2W  = (const float*)d_in[10];
  const float* d2b  = (const float*)d_in[11];
  const float* fc2W = (const float*)d_in[12];
  const float* fc2b = (const float*)d_in[13];
  (void)in_sizes; (void)n_in; (void)out_size; (void)ws_size;

  float* out  = (float*)d_out;
  float* O_pre = out;
  float* O_enc = out + (long)NG*NH;
  float* O_h   = out + 2L*NG*NH;
  float* O_fin = out + 3L*NG*NH;
  float* O_ls  = O_fin + NH;

  char* p = (char*)d_ws;
  auto alloc = [&](size_t bytes)->void*{
    void* r = (void*)p; p += (bytes + 255) & ~(size_t)255; return r;
  };
  u16* bfA    = (u16*)alloc((size_t)NG*NH*2);
  u16* bfXW   = (u16*)alloc((size_t)NG*NH*2);
  u16* wt_fc1 = (u16*)alloc((size_t)NG*FD*HD*2);
  u16* wt_c1  = (u16*)alloc((size_t)NG*HD*HD*2);
  u16* wt_c2  = (u16*)alloc((size_t)NG*HD*HD*2);
  u16* wt_d1  = (u16*)alloc((size_t)NG*HD*HD*2);
  u16* wt_d2  = (u16*)alloc((size_t)NG*HD*HD*2);
  u16* wt_fc2 = (u16*)alloc((size_t)HD*FD*2);
  int*  cnt    = (int*) alloc((size_t)NG*NV*4);
  int*  cptr   = (int*) alloc((size_t)NG*(NV+1)*4);
  int*  cursor = (int*) alloc((size_t)NG*NV*4);
  int*  csr    = (int*) alloc((size_t)NG*ED*4);
  float* dinv  = (float*)alloc((size_t)NG*NV*4);

  // ---- CSR build (reused by all 4 convs per graph) ----
  zero_u32<<<(NG*NV+255)/256, 256, 0, stream>>>((u32*)cnt, (long)NG*NV);
  count_k<<<(NG*ED+255)/256, 256, 0, stream>>>(ei, cnt);
  scan_k<<<NG, 1024, 0, stream>>>(cnt, cptr, cursor, dinv);
  fill_k<<<(NG*ED+255)/256, 256, 0, stream>>>(ei, cursor, csr);

  // ---- weight transposes to [N][K] bf16 ----
  tr_k<<<(NG*FD*HD+255)/256, 256, 0, stream>>>(fc1W, wt_fc1, FD, HD, (long)NG*FD*HD);
  tr_k<<<(NG*HD*HD+255)/256, 256, 0, stream>>>(c1W, wt_c1, HD, HD, (long)NG*HD*HD);
  tr_k<<<(NG*HD*HD+255)/256, 256, 0, stream>>>(c2W, wt_c2, HD, HD, (long)NG*HD*HD);
  tr_k<<<(NG*HD*HD+255)/256, 256, 0, stream>>>(d1W, wt_d1, HD, HD, (long)NG*HD*HD);
  tr_k<<<(NG*HD*HD+255)/256, 256, 0, stream>>>(d2W, wt_d2, HD, HD, (long)NG*HD*HD);
  tr_k<<<(HD*FD+255)/256, 256, 0, stream>>>(fc2W, wt_fc2, HD, FD, (long)HD*FD);

  dim3 gB((NV+127)/128, 1, NG);   // batched over graphs
  dim3 g1((NV+127)/128, 1, 1);
  dim3 g2((NV+127)/128, 2, 1);

  // ---- encoder (all 3 graphs batched) ----
  gemm_k<1><<<gB, 256, 0, stream>>>(x, (long)NV*FD, wt_fc1, (long)FD*HD, fc1b, HD,
                                    O_pre, NH, bfA, NH, NV, HD, FD);
  gemm_k<0><<<gB, 256, 0, stream>>>(bfA, NH, wt_c1, (long)HD*HD, nullptr, 0,
                                    nullptr, 0, bfXW, NH, NV, HD, HD);
  agg_k<<<NG*NV/4, 256, 0, stream>>>(bfXW, NH, cptr, csr, dinv, c1b, HD,
                                     nullptr, 0, bfA, NH, NV, ED, NG*NV, 0);
  gemm_k<0><<<gB, 256, 0, stream>>>(bfA, NH, wt_c2, (long)HD*HD, nullptr, 0,
                                    nullptr, 0, bfXW, NH, NV, HD, HD);
  agg_k<<<NG*NV/4, 256, 0, stream>>>(bfXW, NH, cptr, csr, dinv, c2b, HD,
                                     O_enc, NH, nullptr, 0, NV, ED, NG*NV, 1);

  // ---- decoder (sequential; h0,h1 feed later iterations) ----
  for (int i=0; i<NG; i++){
    if (i == 0)      ew_neg2<<<NH/4/256, 256, 0, stream>>>((const float4*)O_enc, (const float4*)(O_enc+NH), bfA, NH/4);
    else if (i == 1) ew_neg2<<<NH/4/256, 256, 0, stream>>>((const float4*)(O_enc+NH), (const float4*)O_h, bfA, NH/4);
    else             zero_u32<<<(NH/2+255)/256, 256, 0, stream>>>((u32*)bfA, NH/2);

    const int* cp = cptr + (long)i*(NV+1);
    const int* cs = csr  + (long)i*ED;
    const float* dv = dinv + (long)i*NV;
    gemm_k<0><<<g1, 256, 0, stream>>>(bfA, 0, wt_d1 + (long)i*HD*HD, 0, nullptr, 0,
                                      nullptr, 0, bfXW, 0, NV, HD, HD);
    agg_k<<<NV/4, 256, 0, stream>>>(bfXW, 0, cp, cs, dv, d1b + i*HD, 0,
                                    nullptr, 0, bfA, 0, NV, ED, NV, 0);
    gemm_k<0><<<g1, 256, 0, stream>>>(bfA, 0, wt_d2 + (long)i*HD*HD, 0, nullptr, 0,
                                      nullptr, 0, bfXW, 0, NV, HD, HD);
    agg_k<<<NV/4, 256, 0, stream>>>(bfXW, 0, cp, cs, dv, d2b + i*HD, 0,
                                    O_h + (long)i*NH, 0, nullptr, 0, NV, ED, NV, 0);
  }

  // ---- fin + fc2 + softmax ----
  ew_fin<<<NH/4/256, 256, 0, stream>>>((const float4*)O_h, (const float4*)(O_h+NH),
                                       (float4*)O_fin, bfA, NH/4);
  gemm_k<0><<<g2, 256, 0, stream>>>(bfA, 0, wt_fc2, 0, fc2b, 0,
                                    O_ls, 0, nullptr, 0, NV, FD, HD);
  softmax_k<<<NV/4, 256, 0, stream>>>(O_ls, NV);
}